// Round 7
// baseline (197.090 us; speedup 1.0000x reference)
//
#include <hip/hip_runtime.h>

typedef short bf16x8 __attribute__((ext_vector_type(8)));
typedef float f32x4 __attribute__((ext_vector_type(4)));

#define MFMA16(a, b, c) __builtin_amdgcn_mfma_f32_16x16x32_bf16(a, b, c, 0, 0, 0)

__device__ __forceinline__ unsigned short f2bf(float f) {
    unsigned int u = __float_as_uint(f);
    u += 0x7FFFu + ((u >> 16) & 1u);   // round-to-nearest-even
    return (unsigned short)(u >> 16);
}
// packed pair: low16 = bf16(a), high16 = bf16(b)
__device__ __forceinline__ unsigned int f2bf2(float a, float b) {
    unsigned int ua = __float_as_uint(a);
    ua += 0x7FFFu + ((ua >> 16) & 1u);
    unsigned int ub = __float_as_uint(b);
    ub += 0x7FFFu + ((ub >> 16) & 1u);
    return (ua >> 16) | (ub & 0xFFFF0000u);
}
#define DPPADD(v, CTRL)                                                        \
    {                                                                          \
        int _t = __builtin_amdgcn_mov_dpp(__float_as_int(v), CTRL, 0xf, 0xf, true); \
        v += __int_as_float(_t);                                               \
    }

// ---------------- workspace layout (bytes) ----------------
#define WQT_OFF 0        // ushort[576*192]  W_qkv^T bf16, Q rows pre-scaled by scale*log2e
#define WOT_OFF 221184   // ushort[192*192]  W_out^T  bf16
#define BQ_OFF  294912   // float[576]       b_qkv, Q part pre-scaled
#define TBL_OFF 297216   // float[6*4*64*16] bias table [h][mb][lane][f][r], *log2e
// total 395520 bytes

// ================= prep: weight transpose + bias table =================
__global__ void prep_kernel(const float* __restrict__ Wqkv,
                            const float* __restrict__ bqkv,
                            const float* __restrict__ Wout,
                            const float* __restrict__ rel,
                            unsigned short* __restrict__ WqT,
                            unsigned short* __restrict__ WoT,
                            float* __restrict__ bq,
                            float* __restrict__ tblB) {
    __shared__ float tile[32][33];
    const float LOG2E = 1.4426950408889634f;
    const float SCALE = 0.17677669529663687f * 1.4426950408889634f; // 1/sqrt(32)*log2e
    int bid = blockIdx.x;
    int tx = threadIdx.x & 31, ty = threadIdx.x >> 5;
    if (bid < 108) {                       // W_qkv [192][576] -> WqT [576][192]
        int tn = bid % 18, tc = bid / 18;
#pragma unroll
        for (int i = 0; i < 4; ++i)
            tile[ty + i * 8][tx] = Wqkv[(tc * 32 + ty + i * 8) * 576 + tn * 32 + tx];
        __syncthreads();
        bool isQ = (tn < 6);
#pragma unroll
        for (int i = 0; i < 4; ++i) {
            float v = tile[tx][ty + i * 8];
            if (isQ) v *= SCALE;
            WqT[(tn * 32 + ty + i * 8) * 192 + tc * 32 + tx] = f2bf(v);
        }
    } else if (bid < 144) {                // W_out [192][192] -> WoT [192][192]
        int bb = bid - 108;
        int tn = bb % 6, tc = bb / 6;
#pragma unroll
        for (int i = 0; i < 4; ++i)
            tile[ty + i * 8][tx] = Wout[(tc * 32 + ty + i * 8) * 192 + tn * 32 + tx];
        __syncthreads();
#pragma unroll
        for (int i = 0; i < 4; ++i)
            WoT[(tn * 32 + ty + i * 8) * 192 + tc * 32 + tx] = f2bf(tile[tx][ty + i * 8]);
    } else if (bid == 144) {
        for (int i = threadIdx.x; i < 576; i += 256) {
            float v = bqkv[i];
            if (i < 192) v *= SCALE;
            bq[i] = v;
        }
    } else {                               // bias table, bid 145..240
        int e = (bid - 145) * 256 + threadIdx.x;   // e = (((h*4+mb)*64+lane)*16 + f*4 + r
        int r = e & 3, f = (e >> 2) & 3;
        int lane = (e >> 4) & 63, mb = (e >> 10) & 3, h = e >> 12;
        int g = lane >> 4, l15 = lane & 15;
        int qy = l15 >> 2, qx = l15 & 3;
        int dz = mb - f + 3, dy = g - qy + 3, dx = r - qx + 3;
        tblB[e] = rel[((h * 7 + dz) * 7 + dy) * 7 + dx] * LOG2E;
    }
}

// ---------------- LDS layout (ushort units) ----------------
// 3-pass head-split (2 heads per pass), <80KB -> 2 blocks/CU.
// sX  frag-linear [kk][g][m][l15][8]        12288 us (live all passes)
// sP  per-wave [16][72] P + invq col        9216 us
// sQK [64][136]: Q local (0..63) | K (64..127) | pad
// sVt [64][72]  V^T local [vch][t]
// sO  [64][72]  attention out [t][local c]
#define OFF_X   0
#define OFF_P   12288
#define OFF_QK  21504
#define OFF_VT  30208
#define OFF_O   34816
#define SMEM_US 39424      // 78848 bytes -> 2 blocks/CU (157696 <= 160K)

__global__ __launch_bounds__(512, 4) void wmsa_kernel(
    const float* __restrict__ x, const float* __restrict__ tblB,
    const float* __restrict__ bout,
    const unsigned short* __restrict__ WqT,
    const unsigned short* __restrict__ WoT,
    const float* __restrict__ bq, float* __restrict__ out) {
    __shared__ __align__(16) unsigned short smem[SMEM_US];

    const int tid = threadIdx.x;
    const int bw = blockIdx.x;
    const int b  = bw >> 9;
    const int w  = bw & 511;
    const int wz = w >> 6, wy = (w >> 3) & 7, wx = w & 7;

    const int lane = tid & 63;
    const int wv   = tid >> 6;     // wave id 0..7
    const int g    = lane >> 4;    // quad id 0..3
    const int l15  = lane & 15;

    // ---------- phase 0: x window fp32 -> bf16 LDS, frag-linear, roll(-2) folded ----------
    {
        int t = tid >> 3, q8 = tid & 7;           // 8 threads per token
        int tz = t >> 4, ty = (t >> 2) & 3, tx = t & 3;
        int gz = (wz * 4 + tz + 2) & 31;
        int gy = (wy * 4 + ty + 2) & 31;
        int gx = (wx * 4 + tx + 2) & 31;
        const float* xp = x + ((((b * 32 + gz) * 32 + gy) * 32 + gx)) * 192;
        int g0 = q8 >> 1, j0 = (q8 & 1) * 4, lt = t & 15;
#pragma unroll
        for (int k = 0; k < 6; ++k) {
            float4 v = *(const float4*)(xp + q8 * 4 + k * 32);
            uint2 pk;
            pk.x = f2bf2(v.x, v.y);
            pk.y = f2bf2(v.z, v.w);
            *(uint2*)&smem[OFF_X + ((((k * 4 + g0) * 4 + tz) * 16 + lt) * 8) + j0] = pk;
        }
    }

    const int mw = wv >> 2, nq = wv & 3;   // phase-3 row-half / col-quarter
    f32x4 acc3[3][2];                      // phase-3 accumulators, live across passes
#pragma unroll
    for (int nbi = 0; nbi < 3; ++nbi) {
        float bo = bout[(nq + nbi * 4) * 16 + l15];
        acc3[nbi][0] = f32x4{bo, bo, bo, bo};
        acc3[nbi][1] = f32x4{bo, bo, bo, bo};
    }

    // phase-2 masks (mb = wv&3 is pass-invariant)
    const bool sz = (wz == 7), sy = (wy == 7), sx = (wx == 7);
    const bool anym = sz | sy | sx;
    const int qy = l15 >> 2, qx = l15 & 3;
    const bool my = sy && ((g < 2) != (qy < 2));
    bool mxr[4], mzy4[4];
    {
        const int mb = wv & 3;
#pragma unroll
        for (int r = 0; r < 4; ++r) mxr[r] = sx && ((r < 2) != (qx < 2));
#pragma unroll
        for (int f = 0; f < 4; ++f) mzy4[f] = (sz && ((mb < 2) != (f < 2))) | my;
    }

    // ---------- pass phase 1: QKV projection for 2 heads ----------
    // Register-peak-engineered: afr held 2 m-blocks at a time (48 VGPR, not 96);
    // V-weight rows reuse the bfr registers after the Q/K part retires.
    auto ph1 = [&](int p) {
        bf16x8 bfr[6];
        {   // Q/K rows for this wave
            int rb = (wv < 4) ? (p * 64 + wv * 16) : (192 + p * 64 + (wv - 4) * 16);
            float4 bq4 = *(const float4*)&bq[rb + g * 4];
            const unsigned short* wp = WqT + (rb + l15) * 192 + g * 8;
#pragma unroll
            for (int kk = 0; kk < 6; ++kk) bfr[kk] = *(const bf16x8*)(wp + kk * 32);
            int colbase = ((wv < 4) ? wv * 16 : 64 + (wv - 4) * 16) + g * 4;
#pragma unroll
            for (int half = 0; half < 2; ++half) {
                bf16x8 afr[2][6];
#pragma unroll
                for (int mi = 0; mi < 2; ++mi)
#pragma unroll
                    for (int kk = 0; kk < 6; ++kk)
                        afr[mi][kk] = *(const bf16x8*)&smem[OFF_X + (((kk * 4 + g) * 4 + (half * 2 + mi)) * 16 + l15) * 8];
#pragma unroll
                for (int mi = 0; mi < 2; ++mi) {
                    f32x4 acc = {bq4.x, bq4.y, bq4.z, bq4.w};
#pragma unroll
                    for (int kk = 0; kk < 6; ++kk) acc = MFMA16(bfr[kk], afr[mi][kk], acc);
                    uint2 pk;
                    pk.x = f2bf2(acc[0], acc[1]);
                    pk.y = f2bf2(acc[2], acc[3]);
                    *(uint2*)&smem[OFF_QK + ((half * 2 + mi) * 16 + l15) * 136 + colbase] = pk;
                }
            }
        }
        if (wv < 4) {                  // V block: normal MFMA -> sVt[vch][t]
            int rb = 384 + p * 64 + wv * 16;
            float biasv = bq[rb + l15];
            const unsigned short* wp = WqT + (rb + l15) * 192 + g * 8;
#pragma unroll
            for (int kk = 0; kk < 6; ++kk) bfr[kk] = *(const bf16x8*)(wp + kk * 32);
#pragma unroll
            for (int half = 0; half < 2; ++half) {
                bf16x8 afr[2][6];
#pragma unroll
                for (int mi = 0; mi < 2; ++mi)
#pragma unroll
                    for (int kk = 0; kk < 6; ++kk)
                        afr[mi][kk] = *(const bf16x8*)&smem[OFF_X + (((kk * 4 + g) * 4 + (half * 2 + mi)) * 16 + l15) * 8];
#pragma unroll
                for (int mi = 0; mi < 2; ++mi) {
                    f32x4 acc = {biasv, biasv, biasv, biasv};
#pragma unroll
                    for (int kk = 0; kk < 6; ++kk) acc = MFMA16(afr[mi][kk], bfr[kk], acc);
                    uint2 pk;
                    pk.x = f2bf2(acc[0], acc[1]);
                    pk.y = f2bf2(acc[2], acc[3]);
                    *(uint2*)&smem[OFF_VT + (wv * 16 + l15) * 72 + (half * 2 + mi) * 16 + g * 4] = pk;
                }
            }
        }
    };

    // ---------- pass phase 2: one attention unit per wave ----------
    auto ph2 = [&](int p) {
        const int hl = wv >> 2, mb = wv & 3;
        // bias rows for this pass (L2-resident table; one exposed load per pass)
        f32x4 bv[4];
        {
            int h = 2 * p + hl;
            const f32x4* tp = (const f32x4*)(tblB + ((h * 4 + mb) * 64 + lane) * 16);
#pragma unroll
            for (int f = 0; f < 4; ++f) bv[f] = tp[f];
        }
        unsigned short* pb = &smem[OFF_P + wv * 1152];
        bf16x8 qf = *(const bf16x8*)&smem[OFF_QK + (mb * 16 + l15) * 136 + hl * 32 + g * 8];
        bf16x8 kf[4];
#pragma unroll
        for (int f = 0; f < 4; ++f)
            kf[f] = *(const bf16x8*)&smem[OFF_QK + (f * 16 + l15) * 136 + 64 + hl * 32 + g * 8];
        const int vtb = OFF_VT + (hl * 32 + l15) * 72 + g * 8;
        bf16x8 v00 = *(const bf16x8*)&smem[vtb];
        bf16x8 v01 = *(const bf16x8*)&smem[vtb + 32];
        bf16x8 v10 = *(const bf16x8*)&smem[vtb + 16 * 72];
        bf16x8 v11 = *(const bf16x8*)&smem[vtb + 16 * 72 + 32];

        f32x4 s[4];
#pragma unroll
        for (int f = 0; f < 4; ++f) {
            f32x4 z = {0.f, 0.f, 0.f, 0.f};
            s[f] = MFMA16(qf, kf[f], z);
        }
        if (!anym) {
#pragma unroll
            for (int f = 0; f < 4; ++f)
#pragma unroll
                for (int r = 0; r < 4; ++r)
                    s[f][r] = exp2f(s[f][r] + bv[f][r]);
        } else {
#pragma unroll
            for (int f = 0; f < 4; ++f)
#pragma unroll
                for (int r = 0; r < 4; ++r) {
                    float v = s[f][r] + bv[f][r];
                    v = (mzy4[f] | mxr[r]) ? -1e30f : v;
                    s[f][r] = exp2f(v);
                }
        }
        // row sums via DPP; sm4[r] = rowsum(q = g*4+r) valid in all lanes
        float sm4[4];
#pragma unroll
        for (int r = 0; r < 4; ++r) {
            float sm = (s[0][r] + s[1][r]) + (s[2][r] + s[3][r]);
            DPPADD(sm, 0xB1);    // quad_perm [1,0,3,2]
            DPPADD(sm, 0x4E);    // quad_perm [2,3,0,1]
            DPPADD(sm, 0x124);   // row_ror:4
            DPPADD(sm, 0x128);   // row_ror:8
            sm4[r] = sm;
        }
        const int rq = l15 & 3;
        float ssel = sm4[0];
        ssel = (rq == 1) ? sm4[1] : ssel;
        ssel = (rq == 2) ? sm4[2] : ssel;
        ssel = (rq == 3) ? sm4[3] : ssel;
        float vsel = __builtin_amdgcn_rcpf(ssel);   // 1/rowsum(g*4 + rq)
        if (l15 < 4) *(float*)&pb[(g * 4 + l15) * 72 + 64] = vsel;
        // P (C-layout) -> per-wave LDS -> A-frags (same wave, no barrier)
#pragma unroll
        for (int f = 0; f < 4; ++f) {
            unsigned int u01 = f2bf2(s[f][0], s[f][1]);
            unsigned int u23 = f2bf2(s[f][2], s[f][3]);
            unsigned short* pw = &pb[(g * 4) * 72 + f * 16 + l15];
            pw[0]   = (unsigned short)u01;
            pw[72]  = (unsigned short)(u01 >> 16);
            pw[144] = (unsigned short)u23;
            pw[216] = (unsigned short)(u23 >> 16);
        }
        float invq = *(float*)&pb[l15 * 72 + 64];
        bf16x8 pf0 = *(const bf16x8*)&pb[l15 * 72 + g * 8];
        bf16x8 pf1 = *(const bf16x8*)&pb[l15 * 72 + 32 + g * 8];
        // PV swapped: lane = q-token, regs = 4 consecutive channels
        f32x4 o0 = {0.f, 0.f, 0.f, 0.f}, o1 = {0.f, 0.f, 0.f, 0.f};
        o0 = MFMA16(v00, pf0, o0);
        o1 = MFMA16(v10, pf0, o1);
        o0 = MFMA16(v01, pf1, o0);
        o1 = MFMA16(v11, pf1, o1);
#pragma unroll
        for (int r = 0; r < 4; ++r) { o0[r] *= invq; o1[r] *= invq; }
        unsigned short* ow = &smem[OFF_O + (mb * 16 + l15) * 72 + hl * 32 + g * 4];
        uint2 pa;
        pa.x = f2bf2(o0[0], o0[1]);
        pa.y = f2bf2(o0[2], o0[3]);
        *(uint2*)ow = pa;
        uint2 pc;
        pc.x = f2bf2(o1[0], o1[1]);
        pc.y = f2bf2(o1[2], o1[3]);
        *(uint2*)(ow + 16) = pc;
    };

    // ---------- pass phase 3: accumulate out-projection partial (K-slice p) ----------
    auto ph3a = [&](int p) {
        bf16x8 ofr[2][2];
#pragma unroll
        for (int mi = 0; mi < 2; ++mi)
#pragma unroll
            for (int kkl = 0; kkl < 2; ++kkl)
                ofr[mi][kkl] = *(const bf16x8*)&smem[OFF_O + ((mw * 2 + mi) * 16 + l15) * 72 + kkl * 32 + g * 8];
#pragma unroll
        for (int nbi = 0; nbi < 3; ++nbi) {
            int col = (nq + nbi * 4) * 16 + l15;
            const unsigned short* wp = WoT + col * 192 + p * 64 + g * 8;
            bf16x8 w0 = *(const bf16x8*)wp;
            bf16x8 w1 = *(const bf16x8*)(wp + 32);
            acc3[nbi][0] = MFMA16(ofr[0][0], w0, acc3[nbi][0]);
            acc3[nbi][1] = MFMA16(ofr[1][0], w0, acc3[nbi][1]);
            acc3[nbi][0] = MFMA16(ofr[0][1], w1, acc3[nbi][0]);
            acc3[nbi][1] = MFMA16(ofr[1][1], w1, acc3[nbi][1]);
        }
    };

    __syncthreads();
    ph1(0);
    __syncthreads();
    ph2(0);
    __syncthreads();
    ph3a(0);
    ph1(1);
    __syncthreads();
    ph2(1);
    __syncthreads();
    ph3a(1);
    ph1(2);
    __syncthreads();
    ph2(2);
    __syncthreads();
    ph3a(2);

    // ---------- final: scatter out (roll(+2) folded) ----------
#pragma unroll
    for (int nbi = 0; nbi < 3; ++nbi) {
        int col = (nq + nbi * 4) * 16 + l15;
#pragma unroll
        for (int mi = 0; mi < 2; ++mi) {
            int m = mw * 2 + mi;                    // token t = m*16 + g*4 + r
            int gz = (wz * 4 + m + 2) & 31;
            int gy = (wy * 4 + g + 2) & 31;
#pragma unroll
            for (int r = 0; r < 4; ++r) {
                int gx = (wx * 4 + r + 2) & 31;
                out[(((b * 32 + gz) * 32 + gy) * 32 + gx) * 192 + col] = acc3[nbi][mi][r];
            }
        }
    }
}

extern "C" void kernel_launch(void* const* d_in, const int* in_sizes, int n_in,
                              void* d_out, int out_size, void* d_ws, size_t ws_size,
                              hipStream_t stream) {
    const float* x    = (const float*)d_in[0];
    const float* Wqkv = (const float*)d_in[1];
    const float* bqkv = (const float*)d_in[2];
    const float* rel  = (const float*)d_in[3];
    const float* Wout = (const float*)d_in[4];
    const float* bout = (const float*)d_in[5];

    unsigned short* WqT = (unsigned short*)((char*)d_ws + WQT_OFF);
    unsigned short* WoT = (unsigned short*)((char*)d_ws + WOT_OFF);
    float*          bq  = (float*)((char*)d_ws + BQ_OFF);
    float*          tbl = (float*)((char*)d_ws + TBL_OFF);
    float*          out = (float*)d_out;

    prep_kernel<<<241, 256, 0, stream>>>(Wqkv, bqkv, Wout, rel, WqT, WoT, bq, tbl);
    wmsa_kernel<<<1024, 512, 0, stream>>>(x, tbl, bout, WqT, WoT, bq, out);
}

// Round 9
// 171.786 us; speedup vs baseline: 1.1473x; 1.1473x over previous
//
#include <hip/hip_runtime.h>

typedef short bf16x8 __attribute__((ext_vector_type(8)));
typedef float f32x4 __attribute__((ext_vector_type(4)));

#define MFMA16(a, b, c) __builtin_amdgcn_mfma_f32_16x16x32_bf16(a, b, c, 0, 0, 0)

__device__ __forceinline__ unsigned short f2bf(float f) {
    unsigned int u = __float_as_uint(f);
    u += 0x7FFFu + ((u >> 16) & 1u);   // round-to-nearest-even
    return (unsigned short)(u >> 16);
}
// packed pair: low16 = bf16(a), high16 = bf16(b)
__device__ __forceinline__ unsigned int f2bf2(float a, float b) {
    unsigned int ua = __float_as_uint(a);
    ua += 0x7FFFu + ((ua >> 16) & 1u);
    unsigned int ub = __float_as_uint(b);
    ub += 0x7FFFu + ((ub >> 16) & 1u);
    return (ua >> 16) | (ub & 0xFFFF0000u);
}
#define DPPADD(v, CTRL)                                                        \
    {                                                                          \
        int _t = __builtin_amdgcn_mov_dpp(__float_as_int(v), CTRL, 0xf, 0xf, true); \
        v += __int_as_float(_t);                                               \
    }

// ---------------- workspace layout (bytes) ----------------
#define WQT_OFF 0        // ushort[576*192]  W_qkv^T bf16, Q rows pre-scaled by scale*log2e
#define WOT_OFF 221184   // ushort[192*192]  W_out^T  bf16
#define BQ_OFF  294912   // float[576]       b_qkv, Q part pre-scaled
#define TBL_OFF 297216   // float[6*4*64*16] bias table [h][mb][lane][f][r], *log2e
// total 395520 bytes

// ================= prep: weight transpose + bias table =================
__global__ void prep_kernel(const float* __restrict__ Wqkv,
                            const float* __restrict__ bqkv,
                            const float* __restrict__ Wout,
                            const float* __restrict__ rel,
                            unsigned short* __restrict__ WqT,
                            unsigned short* __restrict__ WoT,
                            float* __restrict__ bq,
                            float* __restrict__ tblB) {
    __shared__ float tile[32][33];
    const float LOG2E = 1.4426950408889634f;
    const float SCALE = 0.17677669529663687f * 1.4426950408889634f; // 1/sqrt(32)*log2e
    int bid = blockIdx.x;
    int tx = threadIdx.x & 31, ty = threadIdx.x >> 5;
    if (bid < 108) {                       // W_qkv [192][576] -> WqT [576][192]
        int tn = bid % 18, tc = bid / 18;
#pragma unroll
        for (int i = 0; i < 4; ++i)
            tile[ty + i * 8][tx] = Wqkv[(tc * 32 + ty + i * 8) * 576 + tn * 32 + tx];
        __syncthreads();
        bool isQ = (tn < 6);
#pragma unroll
        for (int i = 0; i < 4; ++i) {
            float v = tile[tx][ty + i * 8];
            if (isQ) v *= SCALE;
            WqT[(tn * 32 + ty + i * 8) * 192 + tc * 32 + tx] = f2bf(v);
        }
    } else if (bid < 144) {                // W_out [192][192] -> WoT [192][192]
        int bb = bid - 108;
        int tn = bb % 6, tc = bb / 6;
#pragma unroll
        for (int i = 0; i < 4; ++i)
            tile[ty + i * 8][tx] = Wout[(tc * 32 + ty + i * 8) * 192 + tn * 32 + tx];
        __syncthreads();
#pragma unroll
        for (int i = 0; i < 4; ++i)
            WoT[(tn * 32 + ty + i * 8) * 192 + tc * 32 + tx] = f2bf(tile[tx][ty + i * 8]);
    } else if (bid == 144) {
        for (int i = threadIdx.x; i < 576; i += 256) {
            float v = bqkv[i];
            if (i < 192) v *= SCALE;
            bq[i] = v;
        }
    } else {                               // bias table, bid 145..240
        int e = (bid - 145) * 256 + threadIdx.x;   // e = (((h*4+mb)*64+lane)*16 + f*4 + r
        int r = e & 3, f = (e >> 2) & 3;
        int lane = (e >> 4) & 63, mb = (e >> 10) & 3, h = e >> 12;
        int g = lane >> 4, l15 = lane & 15;
        int qy = l15 >> 2, qx = l15 & 3;
        int dz = mb - f + 3, dy = g - qy + 3, dx = r - qx + 3;
        tblB[e] = rel[((h * 7 + dz) * 7 + dy) * 7 + dx] * LOG2E;
    }
}

// ---------------- LDS layout (ushort units) ----------------
// 3-pass head-split (2 heads per pass), <80KB -> 2 blocks/CU.
// sX  frag-linear [kk][g][m][l15][8]        12288 us (live all passes)
// sP  per-wave [16][72] P + invq col        9216 us
// sQK [64][136]: Q local (0..63) | K (64..127) | pad
// sVt [64][72]  V^T local [vch][t]
// sO  [64][72]  attention out [t][local c]
#define OFF_X   0
#define OFF_P   12288
#define OFF_QK  21504
#define OFF_VT  30208
#define OFF_O   34816
#define SMEM_US 39424      // 78848 bytes -> 2 blocks/CU (157696 <= 160K)

// NOTE (measured R3/R6/R7): on this toolchain __launch_bounds__'s 2nd arg acts
// like CUDA's MIN BLOCKS PER CU: (512,4) capped VGPRs at 64 (=512/8waves) and
// forced ~200MB of scratch spills; (512,2) caps at 128, which our ~110-reg
// peak fits. LDS 78.8KB also allows exactly 2 blocks/CU.
__global__ __launch_bounds__(512, 2) void wmsa_kernel(
    const float* __restrict__ x, const float* __restrict__ tblB,
    const float* __restrict__ bout,
    const unsigned short* __restrict__ WqT,
    const unsigned short* __restrict__ WoT,
    const float* __restrict__ bq, float* __restrict__ out) {
    __shared__ __align__(16) unsigned short smem[SMEM_US];

    const int tid = threadIdx.x;
    const int bw = blockIdx.x;
    const int b  = bw >> 9;
    const int w  = bw & 511;
    const int wz = w >> 6, wy = (w >> 3) & 7, wx = w & 7;

    const int lane = tid & 63;
    const int wv   = tid >> 6;     // wave id 0..7
    const int g    = lane >> 4;    // quad id 0..3
    const int l15  = lane & 15;

    // ---------- phase 0: x window fp32 -> bf16 LDS, frag-linear, roll(-2) folded ----------
    {
        int t = tid >> 3, q8 = tid & 7;           // 8 threads per token
        int tz = t >> 4, ty = (t >> 2) & 3, tx = t & 3;
        int gz = (wz * 4 + tz + 2) & 31;
        int gy = (wy * 4 + ty + 2) & 31;
        int gx = (wx * 4 + tx + 2) & 31;
        const float* xp = x + ((((b * 32 + gz) * 32 + gy) * 32 + gx)) * 192;
        int g0 = q8 >> 1, j0 = (q8 & 1) * 4, lt = t & 15;
#pragma unroll
        for (int k = 0; k < 6; ++k) {
            float4 v = *(const float4*)(xp + q8 * 4 + k * 32);
            uint2 pk;
            pk.x = f2bf2(v.x, v.y);
            pk.y = f2bf2(v.z, v.w);
            *(uint2*)&smem[OFF_X + ((((k * 4 + g0) * 4 + tz) * 16 + lt) * 8) + j0] = pk;
        }
    }

    const int mw = wv >> 2, nq = wv & 3;   // phase-3 row-half / col-quarter
    f32x4 acc3[3][2];                      // phase-3 accumulators, live across passes
#pragma unroll
    for (int nbi = 0; nbi < 3; ++nbi) {
        float bo = bout[(nq + nbi * 4) * 16 + l15];
        acc3[nbi][0] = f32x4{bo, bo, bo, bo};
        acc3[nbi][1] = f32x4{bo, bo, bo, bo};
    }

    // phase-2 masks (mb = wv&3 is pass-invariant)
    const bool sz = (wz == 7), sy = (wy == 7), sx = (wx == 7);
    const bool anym = sz | sy | sx;
    const int qy = l15 >> 2, qx = l15 & 3;
    const bool my = sy && ((g < 2) != (qy < 2));
    bool mxr[4], mzy4[4];
    {
        const int mb = wv & 3;
#pragma unroll
        for (int r = 0; r < 4; ++r) mxr[r] = sx && ((r < 2) != (qx < 2));
#pragma unroll
        for (int f = 0; f < 4; ++f) mzy4[f] = (sz && ((mb < 2) != (f < 2))) | my;
    }

    // ---------- pass phase 1: QKV projection for 2 heads ----------
    // Register-peak-engineered: afr held 2 m-blocks at a time (48 VGPR, not 96);
    // V-weight rows reuse the bfr registers after the Q/K part retires.
    auto ph1 = [&](int p) {
        bf16x8 bfr[6];
        {   // Q/K rows for this wave
            int rb = (wv < 4) ? (p * 64 + wv * 16) : (192 + p * 64 + (wv - 4) * 16);
            float4 bq4 = *(const float4*)&bq[rb + g * 4];
            const unsigned short* wp = WqT + (rb + l15) * 192 + g * 8;
#pragma unroll
            for (int kk = 0; kk < 6; ++kk) bfr[kk] = *(const bf16x8*)(wp + kk * 32);
            int colbase = ((wv < 4) ? wv * 16 : 64 + (wv - 4) * 16) + g * 4;
#pragma unroll
            for (int half = 0; half < 2; ++half) {
                bf16x8 afr[2][6];
#pragma unroll
                for (int mi = 0; mi < 2; ++mi)
#pragma unroll
                    for (int kk = 0; kk < 6; ++kk)
                        afr[mi][kk] = *(const bf16x8*)&smem[OFF_X + (((kk * 4 + g) * 4 + (half * 2 + mi)) * 16 + l15) * 8];
#pragma unroll
                for (int mi = 0; mi < 2; ++mi) {
                    f32x4 acc = {bq4.x, bq4.y, bq4.z, bq4.w};
#pragma unroll
                    for (int kk = 0; kk < 6; ++kk) acc = MFMA16(bfr[kk], afr[mi][kk], acc);
                    uint2 pk;
                    pk.x = f2bf2(acc[0], acc[1]);
                    pk.y = f2bf2(acc[2], acc[3]);
                    *(uint2*)&smem[OFF_QK + ((half * 2 + mi) * 16 + l15) * 136 + colbase] = pk;
                }
            }
        }
        if (wv < 4) {                  // V block: normal MFMA -> sVt[vch][t]
            int rb = 384 + p * 64 + wv * 16;
            float biasv = bq[rb + l15];
            const unsigned short* wp = WqT + (rb + l15) * 192 + g * 8;
#pragma unroll
            for (int kk = 0; kk < 6; ++kk) bfr[kk] = *(const bf16x8*)(wp + kk * 32);
#pragma unroll
            for (int half = 0; half < 2; ++half) {
                bf16x8 afr[2][6];
#pragma unroll
                for (int mi = 0; mi < 2; ++mi)
#pragma unroll
                    for (int kk = 0; kk < 6; ++kk)
                        afr[mi][kk] = *(const bf16x8*)&smem[OFF_X + (((kk * 4 + g) * 4 + (half * 2 + mi)) * 16 + l15) * 8];
#pragma unroll
                for (int mi = 0; mi < 2; ++mi) {
                    f32x4 acc = {biasv, biasv, biasv, biasv};
#pragma unroll
                    for (int kk = 0; kk < 6; ++kk) acc = MFMA16(afr[mi][kk], bfr[kk], acc);
                    uint2 pk;
                    pk.x = f2bf2(acc[0], acc[1]);
                    pk.y = f2bf2(acc[2], acc[3]);
                    *(uint2*)&smem[OFF_VT + (wv * 16 + l15) * 72 + (half * 2 + mi) * 16 + g * 4] = pk;
                }
            }
        }
    };

    // ---------- pass phase 2: one attention unit per wave ----------
    auto ph2 = [&](int p) {
        const int hl = wv >> 2, mb = wv & 3;
        // bias rows for this pass (L2-resident table; one exposed load per pass)
        f32x4 bv[4];
        {
            int h = 2 * p + hl;
            const f32x4* tp = (const f32x4*)(tblB + ((h * 4 + mb) * 64 + lane) * 16);
#pragma unroll
            for (int f = 0; f < 4; ++f) bv[f] = tp[f];
        }
        unsigned short* pb = &smem[OFF_P + wv * 1152];
        bf16x8 qf = *(const bf16x8*)&smem[OFF_QK + (mb * 16 + l15) * 136 + hl * 32 + g * 8];
        bf16x8 kf[4];
#pragma unroll
        for (int f = 0; f < 4; ++f)
            kf[f] = *(const bf16x8*)&smem[OFF_QK + (f * 16 + l15) * 136 + 64 + hl * 32 + g * 8];
        const int vtb = OFF_VT + (hl * 32 + l15) * 72 + g * 8;
        bf16x8 v00 = *(const bf16x8*)&smem[vtb];
        bf16x8 v01 = *(const bf16x8*)&smem[vtb + 32];
        bf16x8 v10 = *(const bf16x8*)&smem[vtb + 16 * 72];
        bf16x8 v11 = *(const bf16x8*)&smem[vtb + 16 * 72 + 32];

        f32x4 s[4];
#pragma unroll
        for (int f = 0; f < 4; ++f) {
            f32x4 z = {0.f, 0.f, 0.f, 0.f};
            s[f] = MFMA16(qf, kf[f], z);
        }
        if (!anym) {
#pragma unroll
            for (int f = 0; f < 4; ++f)
#pragma unroll
                for (int r = 0; r < 4; ++r)
                    s[f][r] = exp2f(s[f][r] + bv[f][r]);
        } else {
#pragma unroll
            for (int f = 0; f < 4; ++f)
#pragma unroll
                for (int r = 0; r < 4; ++r) {
                    float v = s[f][r] + bv[f][r];
                    v = (mzy4[f] | mxr[r]) ? -1e30f : v;
                    s[f][r] = exp2f(v);
                }
        }
        // row sums via DPP; sm4[r] = rowsum(q = g*4+r) valid in all lanes
        float sm4[4];
#pragma unroll
        for (int r = 0; r < 4; ++r) {
            float sm = (s[0][r] + s[1][r]) + (s[2][r] + s[3][r]);
            DPPADD(sm, 0xB1);    // quad_perm [1,0,3,2]
            DPPADD(sm, 0x4E);    // quad_perm [2,3,0,1]
            DPPADD(sm, 0x124);   // row_ror:4
            DPPADD(sm, 0x128);   // row_ror:8
            sm4[r] = sm;
        }
        const int rq = l15 & 3;
        float ssel = sm4[0];
        ssel = (rq == 1) ? sm4[1] : ssel;
        ssel = (rq == 2) ? sm4[2] : ssel;
        ssel = (rq == 3) ? sm4[3] : ssel;
        float vsel = __builtin_amdgcn_rcpf(ssel);   // 1/rowsum(g*4 + rq)
        if (l15 < 4) *(float*)&pb[(g * 4 + l15) * 72 + 64] = vsel;
        // P (C-layout) -> per-wave LDS -> A-frags (same wave, no barrier)
#pragma unroll
        for (int f = 0; f < 4; ++f) {
            unsigned int u01 = f2bf2(s[f][0], s[f][1]);
            unsigned int u23 = f2bf2(s[f][2], s[f][3]);
            unsigned short* pw = &pb[(g * 4) * 72 + f * 16 + l15];
            pw[0]   = (unsigned short)u01;
            pw[72]  = (unsigned short)(u01 >> 16);
            pw[144] = (unsigned short)u23;
            pw[216] = (unsigned short)(u23 >> 16);
        }
        float invq = *(float*)&pb[l15 * 72 + 64];
        bf16x8 pf0 = *(const bf16x8*)&pb[l15 * 72 + g * 8];
        bf16x8 pf1 = *(const bf16x8*)&pb[l15 * 72 + 32 + g * 8];
        // PV swapped: lane = q-token, regs = 4 consecutive channels
        f32x4 o0 = {0.f, 0.f, 0.f, 0.f}, o1 = {0.f, 0.f, 0.f, 0.f};
        o0 = MFMA16(v00, pf0, o0);
        o1 = MFMA16(v10, pf0, o1);
        o0 = MFMA16(v01, pf1, o0);
        o1 = MFMA16(v11, pf1, o1);
#pragma unroll
        for (int r = 0; r < 4; ++r) { o0[r] *= invq; o1[r] *= invq; }
        unsigned short* ow = &smem[OFF_O + (mb * 16 + l15) * 72 + hl * 32 + g * 4];
        uint2 pa;
        pa.x = f2bf2(o0[0], o0[1]);
        pa.y = f2bf2(o0[2], o0[3]);
        *(uint2*)ow = pa;
        uint2 pc;
        pc.x = f2bf2(o1[0], o1[1]);
        pc.y = f2bf2(o1[2], o1[3]);
        *(uint2*)(ow + 16) = pc;
    };

    // ---------- pass phase 3: accumulate out-projection partial (K-slice p) ----------
    auto ph3a = [&](int p) {
        bf16x8 ofr[2][2];
#pragma unroll
        for (int mi = 0; mi < 2; ++mi)
#pragma unroll
            for (int kkl = 0; kkl < 2; ++kkl)
                ofr[mi][kkl] = *(const bf16x8*)&smem[OFF_O + ((mw * 2 + mi) * 16 + l15) * 72 + kkl * 32 + g * 8];
#pragma unroll
        for (int nbi = 0; nbi < 3; ++nbi) {
            int col = (nq + nbi * 4) * 16 + l15;
            const unsigned short* wp = WoT + col * 192 + p * 64 + g * 8;
            bf16x8 w0 = *(const bf16x8*)wp;
            bf16x8 w1 = *(const bf16x8*)(wp + 32);
            acc3[nbi][0] = MFMA16(ofr[0][0], w0, acc3[nbi][0]);
            acc3[nbi][1] = MFMA16(ofr[1][0], w0, acc3[nbi][1]);
            acc3[nbi][0] = MFMA16(ofr[0][1], w1, acc3[nbi][0]);
            acc3[nbi][1] = MFMA16(ofr[1][1], w1, acc3[nbi][1]);
        }
    };

    __syncthreads();
    ph1(0);
    __syncthreads();
    ph2(0);
    __syncthreads();
    ph3a(0);
    ph1(1);
    __syncthreads();
    ph2(1);
    __syncthreads();
    ph3a(1);
    ph1(2);
    __syncthreads();
    ph2(2);
    __syncthreads();
    ph3a(2);

    // ---------- final: scatter out (roll(+2) folded) ----------
#pragma unroll
    for (int nbi = 0; nbi < 3; ++nbi) {
        int col = (nq + nbi * 4) * 16 + l15;
#pragma unroll
        for (int mi = 0; mi < 2; ++mi) {
            int m = mw * 2 + mi;                    // token t = m*16 + g*4 + r
            int gz = (wz * 4 + m + 2) & 31;
            int gy = (wy * 4 + g + 2) & 31;
#pragma unroll
            for (int r = 0; r < 4; ++r) {
                int gx = (wx * 4 + r + 2) & 31;
                out[(((b * 32 + gz) * 32 + gy) * 32 + gx) * 192 + col] = acc3[nbi][mi][r];
            }
        }
    }
}

extern "C" void kernel_launch(void* const* d_in, const int* in_sizes, int n_in,
                              void* d_out, int out_size, void* d_ws, size_t ws_size,
                              hipStream_t stream) {
    const float* x    = (const float*)d_in[0];
    const float* Wqkv = (const float*)d_in[1];
    const float* bqkv = (const float*)d_in[2];
    const float* rel  = (const float*)d_in[3];
    const float* Wout = (const float*)d_in[4];
    const float* bout = (const float*)d_in[5];

    unsigned short* WqT = (unsigned short*)((char*)d_ws + WQT_OFF);
    unsigned short* WoT = (unsigned short*)((char*)d_ws + WOT_OFF);
    float*          bq  = (float*)((char*)d_ws + BQ_OFF);
    float*          tbl = (float*)((char*)d_ws + TBL_OFF);
    float*          out = (float*)d_out;

    prep_kernel<<<241, 256, 0, stream>>>(Wqkv, bqkv, Wout, rel, WqT, WoT, bq, tbl);
    wmsa_kernel<<<1024, 512, 0, stream>>>(x, tbl, bout, WqT, WoT, bq, out);
}